// Round 1
// baseline (758.522 us; speedup 1.0000x reference)
//
#include <hip/hip_runtime.h>

#define NPTS 100000
#define NB 500
#define KNN 100
#define KPN 15
#define C1 128
#define C2 1024
#define C3 512
#define C4 256

// ---------------------------------------------------------------- gather
__global__ __launch_bounds__(256) void gather_kernel(
    const float* __restrict__ pts, const float* __restrict__ normal,
    const int* __restrict__ index, float* __restrict__ sel,
    float* __restrict__ out2) {
  int b = blockIdx.x * 256 + threadIdx.x;
  if (b >= NB) return;
  int i = index[b];
  sel[b * 3 + 0] = pts[3 * i + 0];
  sel[b * 3 + 1] = pts[3 * i + 1];
  sel[b * 3 + 2] = pts[3 * i + 2];
  out2[b * 3 + 0] = normal[3 * i + 0];
  out2[b * 3 + 1] = normal[3 * i + 1];
  out2[b * 3 + 2] = normal[3 * i + 2];
}

// ---------------------------------------------------------------- kNN
// Exact 100-NN under L-inf via radix-select on float bits (d>=0 so uint
// ordering == float ordering). 3 histogram passes (12/12/8 bits) + collect.
__global__ __launch_bounds__(256) void knn_kernel(
    const float* __restrict__ pts, const float* __restrict__ sel,
    int* __restrict__ nbr) {
  const int b = blockIdx.x;
  const int tid = threadIdx.x;
  __shared__ unsigned hist[4096];
  __shared__ unsigned chunksum[256];
  __shared__ unsigned s_prefix;
  __shared__ int s_kneed;
  __shared__ int s_cntless;
  __shared__ int s_eqcnt;
  __shared__ int eqbuf[64];

  const float sx = sel[b * 3 + 0], sy = sel[b * 3 + 1], sz = sel[b * 3 + 2];

  int kneed = KNN;
  unsigned prefix = 0;

  for (int pass = 0; pass < 3; ++pass) {
    const int nbins = (pass == 2) ? 256 : 4096;
    for (int j = tid; j < nbins; j += 256) hist[j] = 0;
    __syncthreads();
    for (int i = tid; i < NPTS; i += 256) {
      float dx = fabsf(pts[3 * i + 0] - sx);
      float dy = fabsf(pts[3 * i + 1] - sy);
      float dz = fabsf(pts[3 * i + 2] - sz);
      unsigned bits = __float_as_uint(fmaxf(fmaxf(dx, dy), dz));
      unsigned bin;
      bool ok;
      if (pass == 0)      { ok = true;                      bin = bits >> 20; }
      else if (pass == 1) { ok = (bits >> 20) == prefix;    bin = (bits >> 8) & 4095u; }
      else                { ok = (bits >> 8)  == prefix;    bin = bits & 255u; }
      if (ok) atomicAdd(&hist[bin], 1u);
    }
    __syncthreads();
    const int per = nbins / 256;  // 16 or 1
    unsigned csum = 0;
    for (int j = 0; j < per; ++j) csum += hist[tid * per + j];
    chunksum[tid] = csum;
    __syncthreads();
    if (tid == 0) {
      unsigned need = (unsigned)kneed;
      unsigned cum = 0;
      int chunk = 0;
      for (; chunk < 255; ++chunk) {
        if (cum + chunksum[chunk] >= need) break;
        cum += chunksum[chunk];
      }
      int bin = chunk * per;
      for (;; ++bin) {
        if (cum + hist[bin] >= need) break;
        cum += hist[bin];
      }
      s_kneed = (int)(need - cum);
      unsigned br = (unsigned)bin;
      s_prefix = (pass == 0) ? br : (pass == 1) ? ((prefix << 12) | br)
                                                : ((prefix << 8) | br);
    }
    __syncthreads();
    prefix = s_prefix;
    kneed = s_kneed;
    __syncthreads();
  }
  const unsigned V = prefix;  // exact bit pattern of the 100th distance
  if (tid == 0) { s_cntless = 0; s_eqcnt = 0; }
  __syncthreads();
  for (int i = tid; i < NPTS; i += 256) {
    float dx = fabsf(pts[3 * i + 0] - sx);
    float dy = fabsf(pts[3 * i + 1] - sy);
    float dz = fabsf(pts[3 * i + 2] - sz);
    unsigned bits = __float_as_uint(fmaxf(fmaxf(dx, dy), dz));
    if (bits < V) {
      int pos = atomicAdd(&s_cntless, 1);
      if (pos < KNN) nbr[b * KNN + pos] = i;
    } else if (bits == V) {
      int e = atomicAdd(&s_eqcnt, 1);
      if (e < 64) eqbuf[e] = i;
    }
  }
  __syncthreads();
  if (tid == 0) {
    int base = s_cntless;  // == KNN - kneed
    int m = s_eqcnt; if (m > 64) m = 64;
    for (int t = 0; t < kneed; ++t) {  // stable tie-break: lowest index first
      int best = 0x7fffffff, bj = -1;
      for (int j = 0; j < m; ++j)
        if (eqbuf[j] >= 0 && eqbuf[j] < best) { best = eqbuf[j]; bj = j; }
      if (bj >= 0) { eqbuf[bj] = -1; nbr[b * KNN + base + t] = best; }
    }
  }
}

// ---------------------------------------------------------------- KPConv
// h[b*K+k][o] = relu( sum_{p,c} rel[c]*w[p]*kpw[p][c][o] )
__global__ __launch_bounds__(256) void kpconv_kernel(
    const float* __restrict__ pts, const float* __restrict__ sel,
    const int* __restrict__ nbr, const float* __restrict__ kp_points,
    const float* __restrict__ kp_weights, const float* __restrict__ kp_sigma,
    float* __restrict__ h) {
  const int b = blockIdx.x;
  const int tid = threadIdx.x;
  __shared__ float kpw[45 * 128];  // [j=p*3+c][o]
  __shared__ float kpp[45];
  __shared__ float relbuf[2][3];
  __shared__ float abuf[2][45];
  for (int i = tid; i < 45 * 128; i += 256) kpw[i] = kp_weights[i];
  if (tid < 45) kpp[tid] = kp_points[tid];
  const float sg = kp_sigma[0];
  const float inv2s2 = -0.5f / (sg * sg);
  const float sx = sel[b * 3 + 0], sy = sel[b * 3 + 1], sz = sel[b * 3 + 2];
  __syncthreads();
  for (int k0 = 0; k0 < KNN; k0 += 2) {
    if (tid < 2) {
      int idx = nbr[b * KNN + k0 + tid];
      relbuf[tid][0] = pts[3 * idx + 0] - sx;
      relbuf[tid][1] = pts[3 * idx + 1] - sy;
      relbuf[tid][2] = pts[3 * idx + 2] - sz;
    }
    __syncthreads();
    if (tid < 90) {
      int r = tid / 45, j = tid % 45, p = j / 3, c = j % 3;
      float rx = relbuf[r][0] - kpp[p * 3 + 0];
      float ry = relbuf[r][1] - kpp[p * 3 + 1];
      float rz = relbuf[r][2] - kpp[p * 3 + 2];
      float w = expf(inv2s2 * (rx * rx + ry * ry + rz * rz));
      abuf[r][j] = relbuf[r][c] * w;
    }
    __syncthreads();
    {
      int r = tid >> 7, o = tid & 127;
      float acc = 0.f;
#pragma unroll
      for (int j = 0; j < 45; ++j) acc += abuf[r][j] * kpw[j * 128 + o];
      h[(b * KNN + k0 + r) * 128 + o] = fmaxf(acc, 0.f);
    }
    __syncthreads();
  }
}

// ---------------------------------------------------------------- conv1 fused
// y = relu(h @ W^T + bias); per-(b,col) max/min over the 100 neighbors
// (in-block, no atomics) + per-channel sum/sumsq (atomics) for BN stats.
__global__ __launch_bounds__(256) void conv1_kernel(
    const float* __restrict__ h,     // [50000][128]
    const float* __restrict__ w,     // [1024][128]
    const float* __restrict__ bias,  // [1024]
    float* __restrict__ featmax, float* __restrict__ featmin,
    float* __restrict__ bnsum, float* __restrict__ bnsq) {
  const int b = blockIdx.y;
  const int n0 = blockIdx.x * 64;
  const int tid = threadIdx.x;
  const int tc = tid & 15;   // cols 4*tc..4*tc+3
  const int tr = tid >> 4;   // rows 7*tr..7*tr+6 (112 padded rows)
  __shared__ float Hs[112 * 68];  // pad 68 breaks bank conflicts
  __shared__ float Ws[64 * 68];   // Ws[kk][col]
  float acc[7][4];
#pragma unroll
  for (int r = 0; r < 7; ++r)
#pragma unroll
    for (int c = 0; c < 4; ++c) acc[r][c] = 0.f;

  for (int kc = 0; kc < 2; ++kc) {
    __syncthreads();
#pragma unroll
    for (int i = 0; i < 7; ++i) {
      int f = tid + i * 256;           // 0..1791
      int row = f >> 4, kq = (f & 15) * 4;
      float4 v = make_float4(0.f, 0.f, 0.f, 0.f);
      if (row < 100)
        v = *(const float4*)&h[(b * 100 + row) * 128 + kc * 64 + kq];
      *(float4*)&Hs[row * 68 + kq] = v;
    }
#pragma unroll
    for (int i = 0; i < 4; ++i) {
      int f = tid + i * 256;           // 0..1023
      int cr = f >> 4, kq = (f & 15) * 4;
      float4 v = *(const float4*)&w[(n0 + cr) * 128 + kc * 64 + kq];
      Ws[(kq + 0) * 68 + cr] = v.x;
      Ws[(kq + 1) * 68 + cr] = v.y;
      Ws[(kq + 2) * 68 + cr] = v.z;
      Ws[(kq + 3) * 68 + cr] = v.w;
    }
    __syncthreads();
    for (int kk = 0; kk < 64; kk += 4) {
      float4 w0 = *(float4*)&Ws[(kk + 0) * 68 + 4 * tc];
      float4 w1 = *(float4*)&Ws[(kk + 1) * 68 + 4 * tc];
      float4 w2 = *(float4*)&Ws[(kk + 2) * 68 + 4 * tc];
      float4 w3 = *(float4*)&Ws[(kk + 3) * 68 + 4 * tc];
#pragma unroll
      for (int r = 0; r < 7; ++r) {
        float4 hv = *(float4*)&Hs[(7 * tr + r) * 68 + kk];
        acc[r][0] += hv.x * w0.x + hv.y * w1.x + hv.z * w2.x + hv.w * w3.x;
        acc[r][1] += hv.x * w0.y + hv.y * w1.y + hv.z * w2.y + hv.w * w3.y;
        acc[r][2] += hv.x * w0.z + hv.y * w1.z + hv.z * w2.z + hv.w * w3.z;
        acc[r][3] += hv.x * w0.w + hv.y * w1.w + hv.z * w2.w + hv.w * w3.w;
      }
    }
  }
  float bias4[4];
#pragma unroll
  for (int c = 0; c < 4; ++c) bias4[c] = bias[n0 + 4 * tc + c];
  float pmax[4], pmin[4], psum[4], psq[4];
#pragma unroll
  for (int c = 0; c < 4; ++c) {
    pmax[c] = -1e30f; pmin[c] = 1e30f; psum[c] = 0.f; psq[c] = 0.f;
  }
#pragma unroll
  for (int r = 0; r < 7; ++r) {
    int row = 7 * tr + r;
    if (row < 100) {
#pragma unroll
      for (int c = 0; c < 4; ++c) {
        float y = fmaxf(acc[r][c] + bias4[c], 0.f);
        pmax[c] = fmaxf(pmax[c], y);
        pmin[c] = fminf(pmin[c], y);
        psum[c] += y;
        psq[c] += y * y;
      }
    }
  }
  __syncthreads();
  float* red = Hs;  // 4 arrays of [16][68]
#pragma unroll
  for (int c = 0; c < 4; ++c) {
    red[0 * 1088 + tr * 68 + 4 * tc + c] = pmax[c];
    red[1 * 1088 + tr * 68 + 4 * tc + c] = pmin[c];
    red[2 * 1088 + tr * 68 + 4 * tc + c] = psum[c];
    red[3 * 1088 + tr * 68 + 4 * tc + c] = psq[c];
  }
  __syncthreads();
  if (tid < 64) {
    int col = tid;
    float vmax = -1e30f, vmin = 1e30f, vsum = 0.f, vsq = 0.f;
    for (int g = 0; g < 16; ++g) {
      vmax = fmaxf(vmax, red[0 * 1088 + g * 68 + col]);
      vmin = fminf(vmin, red[1 * 1088 + g * 68 + col]);
      vsum += red[2 * 1088 + g * 68 + col];
      vsq += red[3 * 1088 + g * 68 + col];
    }
    featmax[b * C2 + n0 + col] = vmax;
    featmin[b * C2 + n0 + col] = vmin;
    atomicAdd(&bnsum[n0 + col], vsum);
    atomicAdd(&bnsq[n0 + col], vsq);
  }
}

// ------------------------------------------------------- BN1 + max finalize
__global__ __launch_bounds__(256) void bn1max_kernel(
    const float* __restrict__ featmax, const float* __restrict__ featmin,
    const float* __restrict__ bnsum, const float* __restrict__ bnsq,
    const float* __restrict__ g, const float* __restrict__ bb,
    float* __restrict__ feat1) {
  int idx = blockIdx.x * 256 + threadIdx.x;
  if (idx >= NB * C2) return;
  int o = idx & (C2 - 1);
  const float invn = 1.f / (float)(NB * KNN);
  float m = bnsum[o] * invn;
  float v = bnsq[o] * invn - m * m;
  float a = g[o] / sqrtf(v + 1e-5f);
  float x = (a >= 0.f) ? featmax[idx] : featmin[idx];  // max of monotone map
  feat1[idx] = (x - m) * a + bb[o];
}

// ---------------------------------------------------------------- fc + stats
template <int KDIM>
__global__ __launch_bounds__(256) void fc_relu_stats_kernel(
    const float* __restrict__ x,  // [500][KDIM]
    const float* __restrict__ w,  // [N][KDIM]
    const float* __restrict__ bias, float* __restrict__ yraw,
    float* __restrict__ s, float* __restrict__ sq, int ncols) {
  const int r0 = blockIdx.x * 4;
  const int n0 = blockIdx.y * 64;
  const int tid = threadIdx.x;
  const int col = tid >> 2;  // 0..63
  const int row = tid & 3;
  __shared__ float xs[4][1028];
  __shared__ float ws[64][132];
  for (int f = tid; f < KDIM; f += 256) {  // KDIM float4's total
    int rr = f / (KDIM / 4), kq = (f % (KDIM / 4)) * 4;
    *(float4*)&xs[rr][kq] = *(const float4*)&x[(r0 + rr) * KDIM + kq];
  }
  float acc = 0.f;
  for (int kc = 0; kc < KDIM; kc += 128) {
    __syncthreads();
#pragma unroll
    for (int i = 0; i < 8; ++i) {
      int f = tid + i * 256;  // 0..2047
      int cr = f >> 5, kq = (f & 31) * 4;
      *(float4*)&ws[cr][kq] = *(const float4*)&w[(n0 + cr) * KDIM + kc + kq];
    }
    __syncthreads();
    for (int kk = 0; kk < 128; kk += 4) {
      float4 xv = *(float4*)&xs[row][kc + kk];
      float4 wv = *(float4*)&ws[col][kk];
      acc += xv.x * wv.x + xv.y * wv.y + xv.z * wv.z + xv.w * wv.w;
    }
  }
  float y = fmaxf(acc + bias[n0 + col], 0.f);
  yraw[(r0 + row) * ncols + n0 + col] = y;
  float ys = y, y2 = y * y;
  ys += __shfl_xor(ys, 1); y2 += __shfl_xor(y2, 1);
  ys += __shfl_xor(ys, 2); y2 += __shfl_xor(y2, 2);
  if (row == 0) {
    atomicAdd(&s[n0 + col], ys);
    atomicAdd(&sq[n0 + col], y2);
  }
}

// ---------------------------------------------------------------- BN finalize
__global__ __launch_bounds__(256) void bn_finalize_kernel(
    const float* __restrict__ yraw, const float* __restrict__ s,
    const float* __restrict__ sq, const float* __restrict__ g,
    const float* __restrict__ bb, float* __restrict__ out, int ncols) {
  int idx = blockIdx.x * 256 + threadIdx.x;
  if (idx >= NB * ncols) return;
  int o = idx & (ncols - 1);  // ncols is a power of two
  float m = s[o] * (1.f / (float)NB);
  float v = sq[o] * (1.f / (float)NB) - m * m;
  float a = g[o] / sqrtf(v + 1e-5f);
  out[idx] = (yraw[idx] - m) * a + bb[o];
}

// ---------------------------------------------------------------- fc3
__global__ __launch_bounds__(256) void fc3_kernel(
    const float* __restrict__ feat, const float* __restrict__ w,
    const float* __restrict__ bias, float* __restrict__ out) {
  int idx = blockIdx.x * 256 + threadIdx.x;
  if (idx >= NB * 3) return;
  int b = idx / 3, o = idx % 3;
  float acc = 0.f;
  for (int k = 0; k < C4; ++k) acc += feat[b * C4 + k] * w[o * C4 + k];
  out[idx] = acc + bias[o];
}

// ---------------------------------------------------------------- launch
extern "C" void kernel_launch(void* const* d_in, const int* in_sizes, int n_in,
                              void* d_out, int out_size, void* d_ws,
                              size_t ws_size, hipStream_t stream) {
  const float* pts = (const float*)d_in[0];
  const float* normal = (const float*)d_in[1];
  const float* kp_points = (const float*)d_in[2];
  const float* kp_weights = (const float*)d_in[3];
  const float* kp_sigma = (const float*)d_in[4];
  const float* conv1_w = (const float*)d_in[5];
  const float* conv1_b = (const float*)d_in[6];
  const float* bn1_g = (const float*)d_in[7];
  const float* bn1_b = (const float*)d_in[8];
  const float* fc1_w = (const float*)d_in[9];
  const float* fc1_b = (const float*)d_in[10];
  const float* bn4_g = (const float*)d_in[11];
  const float* bn4_b = (const float*)d_in[12];
  const float* fc2_w = (const float*)d_in[13];
  const float* fc2_b = (const float*)d_in[14];
  const float* bn5_g = (const float*)d_in[15];
  const float* bn5_b = (const float*)d_in[16];
  const float* fc3_w = (const float*)d_in[17];
  const float* fc3_b = (const float*)d_in[18];
  const int* index = (const int*)d_in[19];
  float* out = (float*)d_out;

  char* p = (char*)d_ws;
  auto carve = [&](size_t bytes) {
    void* r = (void*)p;
    p += (bytes + 255) & ~(size_t)255;
    return r;
  };
  float* sel = (float*)carve(NB * 3 * 4);
  int* nbr = (int*)carve(NB * KNN * 4);
  float* h = (float*)carve((size_t)NB * KNN * C1 * 4);
  float* featmax = (float*)carve(NB * C2 * 4);
  float* featmin = (float*)carve(NB * C2 * 4);
  float* feat1 = (float*)carve(NB * C2 * 4);
  float* f2raw = (float*)carve(NB * C3 * 4);
  float* feat2 = (float*)carve(NB * C3 * 4);
  float* f3raw = (float*)carve(NB * C4 * 4);
  float* feat3 = (float*)carve(NB * C4 * 4);
  float* stats = (float*)carve((2 * C2 + 2 * C3 + 2 * C4) * 4);
  float* bnsum = stats;
  float* bnsq = stats + C2;
  float* s4 = stats + 2 * C2;
  float* sq4 = s4 + C3;
  float* s5 = sq4 + C3;
  float* sq5 = s5 + C4;

  hipMemsetAsync(stats, 0, (2 * C2 + 2 * C3 + 2 * C4) * 4, stream);

  gather_kernel<<<2, 256, 0, stream>>>(pts, normal, index, sel, out + NB * 3);
  knn_kernel<<<NB, 256, 0, stream>>>(pts, sel, nbr);
  kpconv_kernel<<<NB, 256, 0, stream>>>(pts, sel, nbr, kp_points, kp_weights,
                                        kp_sigma, h);
  conv1_kernel<<<dim3(16, NB), 256, 0, stream>>>(h, conv1_w, conv1_b, featmax,
                                                 featmin, bnsum, bnsq);
  bn1max_kernel<<<(NB * C2 + 255) / 256, 256, 0, stream>>>(
      featmax, featmin, bnsum, bnsq, bn1_g, bn1_b, feat1);
  fc_relu_stats_kernel<C2><<<dim3(125, C3 / 64), 256, 0, stream>>>(
      feat1, fc1_w, fc1_b, f2raw, s4, sq4, C3);
  bn_finalize_kernel<<<(NB * C3 + 255) / 256, 256, 0, stream>>>(
      f2raw, s4, sq4, bn4_g, bn4_b, feat2, C3);
  fc_relu_stats_kernel<C3><<<dim3(125, C4 / 64), 256, 0, stream>>>(
      feat2, fc2_w, fc2_b, f3raw, s5, sq5, C4);
  bn_finalize_kernel<<<(NB * C4 + 255) / 256, 256, 0, stream>>>(
      f3raw, s5, sq5, bn5_g, bn5_b, feat3, C4);
  fc3_kernel<<<(NB * 3 + 255) / 256, 256, 0, stream>>>(feat3, fc3_w, fc3_b,
                                                       out);
}

// Round 2
// 496.602 us; speedup vs baseline: 1.5274x; 1.5274x over previous
//
#include <hip/hip_runtime.h>

#define NPTS 100000
#define NB 500
#define KNN 100
#define KPN 15
#define C1 128
#define C2 1024
#define C3 512
#define C4 256

// ---------------------------------------------------------------- gather
__global__ __launch_bounds__(256) void gather_kernel(
    const float* __restrict__ pts, const float* __restrict__ normal,
    const int* __restrict__ index, float* __restrict__ sel,
    float* __restrict__ out2) {
  int b = blockIdx.x * 256 + threadIdx.x;
  if (b >= NB) return;
  int i = index[b];
  sel[b * 3 + 0] = pts[3 * i + 0];
  sel[b * 3 + 1] = pts[3 * i + 1];
  sel[b * 3 + 2] = pts[3 * i + 2];
  out2[b * 3 + 0] = normal[3 * i + 0];
  out2[b * 3 + 1] = normal[3 * i + 1];
  out2[b * 3 + 2] = normal[3 * i + 2];
}

// ---------------------------------------------------------------- kNN v2
// Exact 100-NN under L-inf. d>=0 so float ordering == uint ordering on the
// raw bits. One 12-bit histogram scan (bits>>19) picks the boundary bin;
// candidates in that bin (expected ~20) are rank-selected exactly in LDS.
// Cold fallback: narrowing passes if a bin ever holds >1024 points.
__device__ __forceinline__ unsigned linf_bits(float px, float py, float pz,
                                              float sx, float sy, float sz) {
  float dx = fabsf(px - sx), dy = fabsf(py - sy), dz = fabsf(pz - sz);
  return __float_as_uint(fmaxf(fmaxf(dx, dy), dz));
}

__global__ __launch_bounds__(256) void knn_kernel(
    const float* __restrict__ pts, const float* __restrict__ sel,
    int* __restrict__ nbr) {
  const int b = blockIdx.x;
  const int tid = threadIdx.x;
  __shared__ unsigned hist[4096];
  __shared__ unsigned chunksum[256];
  __shared__ unsigned s_prefix;
  __shared__ int s_kneed, s_base, s_cnt, s_direct, s_cnt2;
  __shared__ unsigned cand_bits[1024];
  __shared__ int cand_idx[1024];

  const float sx = sel[b * 3 + 0], sy = sel[b * 3 + 1], sz = sel[b * 3 + 2];
  const float4* base4 = (const float4*)pts;

  // ---- scan 1: 12-bit histogram, 8 pts/thread, prefetched float4 loads
  for (int j = tid; j < 4096; j += 256) hist[j] = 0;
  __syncthreads();
  {
    float4 c[6], n[6];
    int i0 = tid * 8;
#pragma unroll
    for (int j = 0; j < 6; ++j) c[j] = base4[(i0 * 3) / 4 + j];
    for (int it = 0; it < 48; ++it) {
      if (it + 1 < 48) {
        int i1 = (it + 1) * 2048 + tid * 8;
#pragma unroll
        for (int j = 0; j < 6; ++j) n[j] = base4[(i1 * 3) / 4 + j];
      }
      float px[8], py[8], pz[8];
      px[0] = c[0].x; py[0] = c[0].y; pz[0] = c[0].z;
      px[1] = c[0].w; py[1] = c[1].x; pz[1] = c[1].y;
      px[2] = c[1].z; py[2] = c[1].w; pz[2] = c[2].x;
      px[3] = c[2].y; py[3] = c[2].z; pz[3] = c[2].w;
      px[4] = c[3].x; py[4] = c[3].y; pz[4] = c[3].z;
      px[5] = c[3].w; py[5] = c[4].x; pz[5] = c[4].y;
      px[6] = c[4].z; py[6] = c[4].w; pz[6] = c[5].x;
      px[7] = c[5].y; py[7] = c[5].z; pz[7] = c[5].w;
#pragma unroll
      for (int j = 0; j < 8; ++j) {
        unsigned bits = linf_bits(px[j], py[j], pz[j], sx, sy, sz);
        atomicAdd(&hist[bits >> 19], 1u);
      }
#pragma unroll
      for (int j = 0; j < 6; ++j) c[j] = n[j];
    }
    for (int i = 98304 + tid; i < NPTS; i += 256) {
      unsigned bits =
          linf_bits(pts[3 * i], pts[3 * i + 1], pts[3 * i + 2], sx, sy, sz);
      atomicAdd(&hist[bits >> 19], 1u);
    }
  }

  // ---- pick boundary bin (+ cold narrowing passes if bin > cap)
  unsigned shift = 19, prefix = 0, pendwidth = 0;
  int kneed = KNN;
  for (int pass = 0;; ++pass) {
    __syncthreads();
    unsigned csum = 0;
    for (int j = 0; j < 16; ++j) csum += hist[tid * 16 + j];
    chunksum[tid] = csum;
    __syncthreads();
    if (tid == 0) {
      unsigned need = (unsigned)s_kneed;  // not yet valid on pass 0
      need = (unsigned)kneed;  // uniform: kneed is uniform across threads
      unsigned cum = 0;
      int chunk = 0;
      while (chunk < 255 && cum + chunksum[chunk] < need) {
        cum += chunksum[chunk];
        ++chunk;
      }
      int bin = chunk * 16;
      while (cum + hist[bin] < need) {
        cum += hist[bin];
        ++bin;
      }
      s_kneed = (int)(need - cum);
      s_base = (int)cum;
      s_prefix = (unsigned)bin;
      s_cnt = (int)hist[bin];
    }
    __syncthreads();
    int bincnt = s_cnt;
    kneed = s_kneed;
    prefix = (pass == 0) ? s_prefix : ((prefix << pendwidth) | s_prefix);
    if (bincnt <= 1024 || shift == 0) break;
    // cold path: narrow within the selected bin
    unsigned fshift = shift;
    unsigned nshift = (shift == 19) ? 7u : 0u;
    pendwidth = (shift == 19) ? 12u : 7u;
    __syncthreads();
    for (int j = tid; j < 4096; j += 256) hist[j] = 0;
    __syncthreads();
    for (int i = tid; i < NPTS; i += 256) {
      unsigned bits =
          linf_bits(pts[3 * i], pts[3 * i + 1], pts[3 * i + 2], sx, sy, sz);
      if ((bits >> fshift) == prefix) {
        unsigned bin = (nshift == 7u) ? ((bits >> 7) & 4095u) : (bits & 127u);
        atomicAdd(&hist[bin], 1u);
      }
    }
    shift = nshift;
  }

  // ---- scan 2: collect definite members + boundary candidates
  if (tid == 0) {
    s_direct = 0;
    s_cnt2 = 0;
  }
  __syncthreads();
  {
    float4 c[6], n[6];
    int i0 = tid * 8;
#pragma unroll
    for (int j = 0; j < 6; ++j) c[j] = base4[(i0 * 3) / 4 + j];
    for (int it = 0; it < 48; ++it) {
      if (it + 1 < 48) {
        int i1 = (it + 1) * 2048 + tid * 8;
#pragma unroll
        for (int j = 0; j < 6; ++j) n[j] = base4[(i1 * 3) / 4 + j];
      }
      float px[8], py[8], pz[8];
      px[0] = c[0].x; py[0] = c[0].y; pz[0] = c[0].z;
      px[1] = c[0].w; py[1] = c[1].x; pz[1] = c[1].y;
      px[2] = c[1].z; py[2] = c[1].w; pz[2] = c[2].x;
      px[3] = c[2].y; py[3] = c[2].z; pz[3] = c[2].w;
      px[4] = c[3].x; py[4] = c[3].y; pz[4] = c[3].z;
      px[5] = c[3].w; py[5] = c[4].x; pz[5] = c[4].y;
      px[6] = c[4].z; py[6] = c[4].w; pz[6] = c[5].x;
      px[7] = c[5].y; py[7] = c[5].z; pz[7] = c[5].w;
      int ibase = it * 2048 + tid * 8;
#pragma unroll
      for (int j = 0; j < 8; ++j) {
        unsigned bits = linf_bits(px[j], py[j], pz[j], sx, sy, sz);
        unsigned v = bits >> shift;
        if (v < prefix) {
          int pos = atomicAdd(&s_direct, 1);
          nbr[b * KNN + pos] = ibase + j;
        } else if (v == prefix) {
          int e = atomicAdd(&s_cnt2, 1);
          if (e < 1024) {
            cand_bits[e] = bits;
            cand_idx[e] = ibase + j;
          }
        }
      }
#pragma unroll
      for (int j = 0; j < 6; ++j) c[j] = n[j];
    }
    for (int i = 98304 + tid; i < NPTS; i += 256) {
      unsigned bits =
          linf_bits(pts[3 * i], pts[3 * i + 1], pts[3 * i + 2], sx, sy, sz);
      unsigned v = bits >> shift;
      if (v < prefix) {
        int pos = atomicAdd(&s_direct, 1);
        nbr[b * KNN + pos] = i;
      } else if (v == prefix) {
        int e = atomicAdd(&s_cnt2, 1);
        if (e < 1024) {
          cand_bits[e] = bits;
          cand_idx[e] = i;
        }
      }
    }
  }
  __syncthreads();

  // ---- exact rank-select among candidates (ties: lowest index, == top_k)
  int m = s_cnt2 < 1024 ? s_cnt2 : 1024;
  int base = s_direct;
  for (int c = tid; c < m; c += 256) {
    unsigned bc = cand_bits[c];
    int ic = cand_idx[c];
    int rank = 0;
    for (int j = 0; j < m; ++j) {
      unsigned bj = cand_bits[j];
      rank += (bj < bc || (bj == bc && cand_idx[j] < ic)) ? 1 : 0;
    }
    if (rank < kneed) nbr[b * KNN + base + rank] = ic;
  }
}

// ---------------------------------------------------------------- KPConv
// h[b*K+k][o] = relu( sum_{p,c} rel[c]*w[p]*kpw[p][c][o] )
__global__ __launch_bounds__(256) void kpconv_kernel(
    const float* __restrict__ pts, const float* __restrict__ sel,
    const int* __restrict__ nbr, const float* __restrict__ kp_points,
    const float* __restrict__ kp_weights, const float* __restrict__ kp_sigma,
    float* __restrict__ h) {
  const int b = blockIdx.x;
  const int tid = threadIdx.x;
  __shared__ float kpw[45 * 128];  // [j=p*3+c][o]
  __shared__ float kpp[45];
  __shared__ float relbuf[2][3];
  __shared__ float abuf[2][45];
  for (int i = tid; i < 45 * 128; i += 256) kpw[i] = kp_weights[i];
  if (tid < 45) kpp[tid] = kp_points[tid];
  const float sg = kp_sigma[0];
  const float inv2s2 = -0.5f / (sg * sg);
  const float sx = sel[b * 3 + 0], sy = sel[b * 3 + 1], sz = sel[b * 3 + 2];
  __syncthreads();
  for (int k0 = 0; k0 < KNN; k0 += 2) {
    if (tid < 2) {
      int idx = nbr[b * KNN + k0 + tid];
      relbuf[tid][0] = pts[3 * idx + 0] - sx;
      relbuf[tid][1] = pts[3 * idx + 1] - sy;
      relbuf[tid][2] = pts[3 * idx + 2] - sz;
    }
    __syncthreads();
    if (tid < 90) {
      int r = tid / 45, j = tid % 45, p = j / 3, c = j % 3;
      float rx = relbuf[r][0] - kpp[p * 3 + 0];
      float ry = relbuf[r][1] - kpp[p * 3 + 1];
      float rz = relbuf[r][2] - kpp[p * 3 + 2];
      float w = expf(inv2s2 * (rx * rx + ry * ry + rz * rz));
      abuf[r][j] = relbuf[r][c] * w;
    }
    __syncthreads();
    {
      int r = tid >> 7, o = tid & 127;
      float acc = 0.f;
#pragma unroll
      for (int j = 0; j < 45; ++j) acc += abuf[r][j] * kpw[j * 128 + o];
      h[(b * KNN + k0 + r) * 128 + o] = fmaxf(acc, 0.f);
    }
    __syncthreads();
  }
}

// ---------------------------------------------------------------- conv1 fused
__global__ __launch_bounds__(256) void conv1_kernel(
    const float* __restrict__ h,     // [50000][128]
    const float* __restrict__ w,     // [1024][128]
    const float* __restrict__ bias,  // [1024]
    float* __restrict__ featmax, float* __restrict__ featmin,
    float* __restrict__ bnsum, float* __restrict__ bnsq) {
  const int b = blockIdx.y;
  const int n0 = blockIdx.x * 64;
  const int tid = threadIdx.x;
  const int tc = tid & 15;   // cols 4*tc..4*tc+3
  const int tr = tid >> 4;   // rows 7*tr..7*tr+6 (112 padded rows)
  __shared__ float Hs[112 * 68];  // pad 68 breaks bank conflicts
  __shared__ float Ws[64 * 68];   // Ws[kk][col]
  float acc[7][4];
#pragma unroll
  for (int r = 0; r < 7; ++r)
#pragma unroll
    for (int c = 0; c < 4; ++c) acc[r][c] = 0.f;

  for (int kc = 0; kc < 2; ++kc) {
    __syncthreads();
#pragma unroll
    for (int i = 0; i < 7; ++i) {
      int f = tid + i * 256;           // 0..1791
      int row = f >> 4, kq = (f & 15) * 4;
      float4 v = make_float4(0.f, 0.f, 0.f, 0.f);
      if (row < 100)
        v = *(const float4*)&h[(b * 100 + row) * 128 + kc * 64 + kq];
      *(float4*)&Hs[row * 68 + kq] = v;
    }
#pragma unroll
    for (int i = 0; i < 4; ++i) {
      int f = tid + i * 256;           // 0..1023
      int cr = f >> 4, kq = (f & 15) * 4;
      float4 v = *(const float4*)&w[(n0 + cr) * 128 + kc * 64 + kq];
      Ws[(kq + 0) * 68 + cr] = v.x;
      Ws[(kq + 1) * 68 + cr] = v.y;
      Ws[(kq + 2) * 68 + cr] = v.z;
      Ws[(kq + 3) * 68 + cr] = v.w;
    }
    __syncthreads();
    for (int kk = 0; kk < 64; kk += 4) {
      float4 w0 = *(float4*)&Ws[(kk + 0) * 68 + 4 * tc];
      float4 w1 = *(float4*)&Ws[(kk + 1) * 68 + 4 * tc];
      float4 w2 = *(float4*)&Ws[(kk + 2) * 68 + 4 * tc];
      float4 w3 = *(float4*)&Ws[(kk + 3) * 68 + 4 * tc];
#pragma unroll
      for (int r = 0; r < 7; ++r) {
        float4 hv = *(float4*)&Hs[(7 * tr + r) * 68 + kk];
        acc[r][0] += hv.x * w0.x + hv.y * w1.x + hv.z * w2.x + hv.w * w3.x;
        acc[r][1] += hv.x * w0.y + hv.y * w1.y + hv.z * w2.y + hv.w * w3.y;
        acc[r][2] += hv.x * w0.z + hv.y * w1.z + hv.z * w2.z + hv.w * w3.z;
        acc[r][3] += hv.x * w0.w + hv.y * w1.w + hv.z * w2.w + hv.w * w3.w;
      }
    }
  }
  float bias4[4];
#pragma unroll
  for (int c = 0; c < 4; ++c) bias4[c] = bias[n0 + 4 * tc + c];
  float pmax[4], pmin[4], psum[4], psq[4];
#pragma unroll
  for (int c = 0; c < 4; ++c) {
    pmax[c] = -1e30f; pmin[c] = 1e30f; psum[c] = 0.f; psq[c] = 0.f;
  }
#pragma unroll
  for (int r = 0; r < 7; ++r) {
    int row = 7 * tr + r;
    if (row < 100) {
#pragma unroll
      for (int c = 0; c < 4; ++c) {
        float y = fmaxf(acc[r][c] + bias4[c], 0.f);
        pmax[c] = fmaxf(pmax[c], y);
        pmin[c] = fminf(pmin[c], y);
        psum[c] += y;
        psq[c] += y * y;
      }
    }
  }
  __syncthreads();
  float* red = Hs;  // 4 arrays of [16][68]
#pragma unroll
  for (int c = 0; c < 4; ++c) {
    red[0 * 1088 + tr * 68 + 4 * tc + c] = pmax[c];
    red[1 * 1088 + tr * 68 + 4 * tc + c] = pmin[c];
    red[2 * 1088 + tr * 68 + 4 * tc + c] = psum[c];
    red[3 * 1088 + tr * 68 + 4 * tc + c] = psq[c];
  }
  __syncthreads();
  if (tid < 64) {
    int col = tid;
    float vmax = -1e30f, vmin = 1e30f, vsum = 0.f, vsq = 0.f;
    for (int g = 0; g < 16; ++g) {
      vmax = fmaxf(vmax, red[0 * 1088 + g * 68 + col]);
      vmin = fminf(vmin, red[1 * 1088 + g * 68 + col]);
      vsum += red[2 * 1088 + g * 68 + col];
      vsq += red[3 * 1088 + g * 68 + col];
    }
    featmax[b * C2 + n0 + col] = vmax;
    featmin[b * C2 + n0 + col] = vmin;
    atomicAdd(&bnsum[n0 + col], vsum);
    atomicAdd(&bnsq[n0 + col], vsq);
  }
}

// ------------------------------------------------------- BN1 + max finalize
__global__ __launch_bounds__(256) void bn1max_kernel(
    const float* __restrict__ featmax, const float* __restrict__ featmin,
    const float* __restrict__ bnsum, const float* __restrict__ bnsq,
    const float* __restrict__ g, const float* __restrict__ bb,
    float* __restrict__ feat1) {
  int idx = blockIdx.x * 256 + threadIdx.x;
  if (idx >= NB * C2) return;
  int o = idx & (C2 - 1);
  const float invn = 1.f / (float)(NB * KNN);
  float m = bnsum[o] * invn;
  float v = bnsq[o] * invn - m * m;
  float a = g[o] / sqrtf(v + 1e-5f);
  float x = (a >= 0.f) ? featmax[idx] : featmin[idx];  // max of monotone map
  feat1[idx] = (x - m) * a + bb[o];
}

// ---------------------------------------------------------------- fc + stats
template <int KDIM>
__global__ __launch_bounds__(256) void fc_relu_stats_kernel(
    const float* __restrict__ x,  // [500][KDIM]
    const float* __restrict__ w,  // [N][KDIM]
    const float* __restrict__ bias, float* __restrict__ yraw,
    float* __restrict__ s, float* __restrict__ sq, int ncols) {
  const int r0 = blockIdx.x * 4;
  const int n0 = blockIdx.y * 64;
  const int tid = threadIdx.x;
  const int col = tid >> 2;  // 0..63
  const int row = tid & 3;
  __shared__ float xs[4][1028];
  __shared__ float ws[64][132];
  for (int f = tid; f < KDIM; f += 256) {  // KDIM float4's total
    int rr = f / (KDIM / 4), kq = (f % (KDIM / 4)) * 4;
    *(float4*)&xs[rr][kq] = *(const float4*)&x[(r0 + rr) * KDIM + kq];
  }
  float acc = 0.f;
  for (int kc = 0; kc < KDIM; kc += 128) {
    __syncthreads();
#pragma unroll
    for (int i = 0; i < 8; ++i) {
      int f = tid + i * 256;  // 0..2047
      int cr = f >> 5, kq = (f & 31) * 4;
      *(float4*)&ws[cr][kq] = *(const float4*)&w[(n0 + cr) * KDIM + kc + kq];
    }
    __syncthreads();
    for (int kk = 0; kk < 128; kk += 4) {
      float4 xv = *(float4*)&xs[row][kc + kk];
      float4 wv = *(float4*)&ws[col][kk];
      acc += xv.x * wv.x + xv.y * wv.y + xv.z * wv.z + xv.w * wv.w;
    }
  }
  float y = fmaxf(acc + bias[n0 + col], 0.f);
  yraw[(r0 + row) * ncols + n0 + col] = y;
  float ys = y, y2 = y * y;
  ys += __shfl_xor(ys, 1); y2 += __shfl_xor(y2, 1);
  ys += __shfl_xor(ys, 2); y2 += __shfl_xor(y2, 2);
  if (row == 0) {
    atomicAdd(&s[n0 + col], ys);
    atomicAdd(&sq[n0 + col], y2);
  }
}

// ---------------------------------------------------------------- BN finalize
__global__ __launch_bounds__(256) void bn_finalize_kernel(
    const float* __restrict__ yraw, const float* __restrict__ s,
    const float* __restrict__ sq, const float* __restrict__ g,
    const float* __restrict__ bb, float* __restrict__ out, int ncols) {
  int idx = blockIdx.x * 256 + threadIdx.x;
  if (idx >= NB * ncols) return;
  int o = idx & (ncols - 1);  // ncols is a power of two
  float m = s[o] * (1.f / (float)NB);
  float v = sq[o] * (1.f / (float)NB) - m * m;
  float a = g[o] / sqrtf(v + 1e-5f);
  out[idx] = (yraw[idx] - m) * a + bb[o];
}

// ---------------------------------------------------------------- fc3
__global__ __launch_bounds__(256) void fc3_kernel(
    const float* __restrict__ feat, const float* __restrict__ w,
    const float* __restrict__ bias, float* __restrict__ out) {
  int idx = blockIdx.x * 256 + threadIdx.x;
  if (idx >= NB * 3) return;
  int b = idx / 3, o = idx % 3;
  float acc = 0.f;
  for (int k = 0; k < C4; ++k) acc += feat[b * C4 + k] * w[o * C4 + k];
  out[idx] = acc + bias[o];
}

// ---------------------------------------------------------------- launch
extern "C" void kernel_launch(void* const* d_in, const int* in_sizes, int n_in,
                              void* d_out, int out_size, void* d_ws,
                              size_t ws_size, hipStream_t stream) {
  const float* pts = (const float*)d_in[0];
  const float* normal = (const float*)d_in[1];
  const float* kp_points = (const float*)d_in[2];
  const float* kp_weights = (const float*)d_in[3];
  const float* kp_sigma = (const float*)d_in[4];
  const float* conv1_w = (const float*)d_in[5];
  const float* conv1_b = (const float*)d_in[6];
  const float* bn1_g = (const float*)d_in[7];
  const float* bn1_b = (const float*)d_in[8];
  const float* fc1_w = (const float*)d_in[9];
  const float* fc1_b = (const float*)d_in[10];
  const float* bn4_g = (const float*)d_in[11];
  const float* bn4_b = (const float*)d_in[12];
  const float* fc2_w = (const float*)d_in[13];
  const float* fc2_b = (const float*)d_in[14];
  const float* bn5_g = (const float*)d_in[15];
  const float* bn5_b = (const float*)d_in[16];
  const float* fc3_w = (const float*)d_in[17];
  const float* fc3_b = (const float*)d_in[18];
  const int* index = (const int*)d_in[19];
  float* out = (float*)d_out;

  char* p = (char*)d_ws;
  auto carve = [&](size_t bytes) {
    void* r = (void*)p;
    p += (bytes + 255) & ~(size_t)255;
    return r;
  };
  float* sel = (float*)carve(NB * 3 * 4);
  int* nbr = (int*)carve(NB * KNN * 4);
  float* h = (float*)carve((size_t)NB * KNN * C1 * 4);
  float* featmax = (float*)carve(NB * C2 * 4);
  float* featmin = (float*)carve(NB * C2 * 4);
  float* feat1 = (float*)carve(NB * C2 * 4);
  float* f2raw = (float*)carve(NB * C3 * 4);
  float* feat2 = (float*)carve(NB * C3 * 4);
  float* f3raw = (float*)carve(NB * C4 * 4);
  float* feat3 = (float*)carve(NB * C4 * 4);
  float* stats = (float*)carve((2 * C2 + 2 * C3 + 2 * C4) * 4);
  float* bnsum = stats;
  float* bnsq = stats + C2;
  float* s4 = stats + 2 * C2;
  float* sq4 = s4 + C3;
  float* s5 = sq4 + C3;
  float* sq5 = s5 + C4;

  hipMemsetAsync(stats, 0, (2 * C2 + 2 * C3 + 2 * C4) * 4, stream);

  gather_kernel<<<2, 256, 0, stream>>>(pts, normal, index, sel, out + NB * 3);
  knn_kernel<<<NB, 256, 0, stream>>>(pts, sel, nbr);
  kpconv_kernel<<<NB, 256, 0, stream>>>(pts, sel, nbr, kp_points, kp_weights,
                                        kp_sigma, h);
  conv1_kernel<<<dim3(16, NB), 256, 0, stream>>>(h, conv1_w, conv1_b, featmax,
                                                 featmin, bnsum, bnsq);
  bn1max_kernel<<<(NB * C2 + 255) / 256, 256, 0, stream>>>(
      featmax, featmin, bnsum, bnsq, bn1_g, bn1_b, feat1);
  fc_relu_stats_kernel<C2><<<dim3(125, C3 / 64), 256, 0, stream>>>(
      feat1, fc1_w, fc1_b, f2raw, s4, sq4, C3);
  bn_finalize_kernel<<<(NB * C3 + 255) / 256, 256, 0, stream>>>(
      f2raw, s4, sq4, bn4_g, bn4_b, feat2, C3);
  fc_relu_stats_kernel<C3><<<dim3(125, C4 / 64), 256, 0, stream>>>(
      feat2, fc2_w, fc2_b, f3raw, s5, sq5, C4);
  bn_finalize_kernel<<<(NB * C4 + 255) / 256, 256, 0, stream>>>(
      f3raw, s5, sq5, bn5_g, bn5_b, feat3, C4);
  fc3_kernel<<<(NB * 3 + 255) / 256, 256, 0, stream>>>(feat3, fc3_w, fc3_b,
                                                       out);
}

// Round 3
// 340.765 us; speedup vs baseline: 2.2259x; 1.4573x over previous
//
#include <hip/hip_runtime.h>
#include <hip/hip_fp16.h>

#define NPTS 100000
#define NB 500
#define KNN 100
#define KPN 15
#define C1 128
#define C2 1024
#define C3 512
#define C4 256

typedef _Float16 half8 __attribute__((ext_vector_type(8)));
typedef float f32x4 __attribute__((ext_vector_type(4)));

// ---------------------------------------------------------------- gather
__global__ __launch_bounds__(256) void gather_kernel(
    const float* __restrict__ pts, const float* __restrict__ normal,
    const int* __restrict__ index, float* __restrict__ sel,
    float* __restrict__ out2) {
  int b = blockIdx.x * 256 + threadIdx.x;
  if (b >= NB) return;
  int i = index[b];
  sel[b * 3 + 0] = pts[3 * i + 0];
  sel[b * 3 + 1] = pts[3 * i + 1];
  sel[b * 3 + 2] = pts[3 * i + 2];
  out2[b * 3 + 0] = normal[3 * i + 0];
  out2[b * 3 + 1] = normal[3 * i + 1];
  out2[b * 3 + 2] = normal[3 * i + 2];
}

// ---------------------------------------------------------------- kNN v2
__device__ __forceinline__ unsigned linf_bits(float px, float py, float pz,
                                              float sx, float sy, float sz) {
  float dx = fabsf(px - sx), dy = fabsf(py - sy), dz = fabsf(pz - sz);
  return __float_as_uint(fmaxf(fmaxf(dx, dy), dz));
}

__global__ __launch_bounds__(256) void knn_kernel(
    const float* __restrict__ pts, const float* __restrict__ sel,
    int* __restrict__ nbr) {
  const int b = blockIdx.x;
  const int tid = threadIdx.x;
  __shared__ unsigned hist[4096];
  __shared__ unsigned chunksum[256];
  __shared__ unsigned s_prefix;
  __shared__ int s_kneed, s_base, s_cnt, s_direct, s_cnt2;
  __shared__ unsigned cand_bits[1024];
  __shared__ int cand_idx[1024];

  const float sx = sel[b * 3 + 0], sy = sel[b * 3 + 1], sz = sel[b * 3 + 2];
  const float4* base4 = (const float4*)pts;

  for (int j = tid; j < 4096; j += 256) hist[j] = 0;
  __syncthreads();
  {
    float4 c[6], n[6];
    int i0 = tid * 8;
#pragma unroll
    for (int j = 0; j < 6; ++j) c[j] = base4[(i0 * 3) / 4 + j];
    for (int it = 0; it < 48; ++it) {
      if (it + 1 < 48) {
        int i1 = (it + 1) * 2048 + tid * 8;
#pragma unroll
        for (int j = 0; j < 6; ++j) n[j] = base4[(i1 * 3) / 4 + j];
      }
      float px[8], py[8], pz[8];
      px[0] = c[0].x; py[0] = c[0].y; pz[0] = c[0].z;
      px[1] = c[0].w; py[1] = c[1].x; pz[1] = c[1].y;
      px[2] = c[1].z; py[2] = c[1].w; pz[2] = c[2].x;
      px[3] = c[2].y; py[3] = c[2].z; pz[3] = c[2].w;
      px[4] = c[3].x; py[4] = c[3].y; pz[4] = c[3].z;
      px[5] = c[3].w; py[5] = c[4].x; pz[5] = c[4].y;
      px[6] = c[4].z; py[6] = c[4].w; pz[6] = c[5].x;
      px[7] = c[5].y; py[7] = c[5].z; pz[7] = c[5].w;
#pragma unroll
      for (int j = 0; j < 8; ++j) {
        unsigned bits = linf_bits(px[j], py[j], pz[j], sx, sy, sz);
        atomicAdd(&hist[bits >> 19], 1u);
      }
#pragma unroll
      for (int j = 0; j < 6; ++j) c[j] = n[j];
    }
    for (int i = 98304 + tid; i < NPTS; i += 256) {
      unsigned bits =
          linf_bits(pts[3 * i], pts[3 * i + 1], pts[3 * i + 2], sx, sy, sz);
      atomicAdd(&hist[bits >> 19], 1u);
    }
  }

  unsigned shift = 19, prefix = 0, pendwidth = 0;
  int kneed = KNN;
  for (int pass = 0;; ++pass) {
    __syncthreads();
    unsigned csum = 0;
    for (int j = 0; j < 16; ++j) csum += hist[tid * 16 + j];
    chunksum[tid] = csum;
    __syncthreads();
    if (tid == 0) {
      unsigned need = (unsigned)kneed;
      unsigned cum = 0;
      int chunk = 0;
      while (chunk < 255 && cum + chunksum[chunk] < need) {
        cum += chunksum[chunk];
        ++chunk;
      }
      int bin = chunk * 16;
      while (cum + hist[bin] < need) {
        cum += hist[bin];
        ++bin;
      }
      s_kneed = (int)(need - cum);
      s_base = (int)cum;
      s_prefix = (unsigned)bin;
      s_cnt = (int)hist[bin];
    }
    __syncthreads();
    int bincnt = s_cnt;
    kneed = s_kneed;
    prefix = (pass == 0) ? s_prefix : ((prefix << pendwidth) | s_prefix);
    if (bincnt <= 1024 || shift == 0) break;
    unsigned fshift = shift;
    unsigned nshift = (shift == 19) ? 7u : 0u;
    pendwidth = (shift == 19) ? 12u : 7u;
    __syncthreads();
    for (int j = tid; j < 4096; j += 256) hist[j] = 0;
    __syncthreads();
    for (int i = tid; i < NPTS; i += 256) {
      unsigned bits =
          linf_bits(pts[3 * i], pts[3 * i + 1], pts[3 * i + 2], sx, sy, sz);
      if ((bits >> fshift) == prefix) {
        unsigned bin = (nshift == 7u) ? ((bits >> 7) & 4095u) : (bits & 127u);
        atomicAdd(&hist[bin], 1u);
      }
    }
    shift = nshift;
  }

  if (tid == 0) {
    s_direct = 0;
    s_cnt2 = 0;
  }
  __syncthreads();
  {
    float4 c[6], n[6];
    int i0 = tid * 8;
#pragma unroll
    for (int j = 0; j < 6; ++j) c[j] = base4[(i0 * 3) / 4 + j];
    for (int it = 0; it < 48; ++it) {
      if (it + 1 < 48) {
        int i1 = (it + 1) * 2048 + tid * 8;
#pragma unroll
        for (int j = 0; j < 6; ++j) n[j] = base4[(i1 * 3) / 4 + j];
      }
      float px[8], py[8], pz[8];
      px[0] = c[0].x; py[0] = c[0].y; pz[0] = c[0].z;
      px[1] = c[0].w; py[1] = c[1].x; pz[1] = c[1].y;
      px[2] = c[1].z; py[2] = c[1].w; pz[2] = c[2].x;
      px[3] = c[2].y; py[3] = c[2].z; pz[3] = c[2].w;
      px[4] = c[3].x; py[4] = c[3].y; pz[4] = c[3].z;
      px[5] = c[3].w; py[5] = c[4].x; pz[5] = c[4].y;
      px[6] = c[4].z; py[6] = c[4].w; pz[6] = c[5].x;
      px[7] = c[5].y; py[7] = c[5].z; pz[7] = c[5].w;
      int ibase = it * 2048 + tid * 8;
#pragma unroll
      for (int j = 0; j < 8; ++j) {
        unsigned bits = linf_bits(px[j], py[j], pz[j], sx, sy, sz);
        unsigned v = bits >> shift;
        if (v < prefix) {
          int pos = atomicAdd(&s_direct, 1);
          nbr[b * KNN + pos] = ibase + j;
        } else if (v == prefix) {
          int e = atomicAdd(&s_cnt2, 1);
          if (e < 1024) {
            cand_bits[e] = bits;
            cand_idx[e] = ibase + j;
          }
        }
      }
#pragma unroll
      for (int j = 0; j < 6; ++j) c[j] = n[j];
    }
    for (int i = 98304 + tid; i < NPTS; i += 256) {
      unsigned bits =
          linf_bits(pts[3 * i], pts[3 * i + 1], pts[3 * i + 2], sx, sy, sz);
      unsigned v = bits >> shift;
      if (v < prefix) {
        int pos = atomicAdd(&s_direct, 1);
        nbr[b * KNN + pos] = i;
      } else if (v == prefix) {
        int e = atomicAdd(&s_cnt2, 1);
        if (e < 1024) {
          cand_bits[e] = bits;
          cand_idx[e] = i;
        }
      }
    }
  }
  __syncthreads();

  int m = s_cnt2 < 1024 ? s_cnt2 : 1024;
  int base = s_direct;
  for (int c = tid; c < m; c += 256) {
    unsigned bc = cand_bits[c];
    int ic = cand_idx[c];
    int rank = 0;
    for (int j = 0; j < m; ++j) {
      unsigned bj = cand_bits[j];
      rank += (bj < bc || (bj == bc && cand_idx[j] < ic)) ? 1 : 0;
    }
    if (rank < kneed) nbr[b * KNN + base + rank] = ic;
  }
}

// ---------------------------------------------------------------- KPConv
// writes h as f16 (consumed by the MFMA conv1)
__global__ __launch_bounds__(256) void kpconv_kernel(
    const float* __restrict__ pts, const float* __restrict__ sel,
    const int* __restrict__ nbr, const float* __restrict__ kp_points,
    const float* __restrict__ kp_weights, const float* __restrict__ kp_sigma,
    __half* __restrict__ h) {
  const int b = blockIdx.x;
  const int tid = threadIdx.x;
  __shared__ float kpw[45 * 128];  // [j=p*3+c][o]
  __shared__ float kpp[45];
  __shared__ float relbuf[2][3];
  __shared__ float abuf[2][45];
  for (int i = tid; i < 45 * 128; i += 256) kpw[i] = kp_weights[i];
  if (tid < 45) kpp[tid] = kp_points[tid];
  const float sg = kp_sigma[0];
  const float inv2s2 = -0.5f / (sg * sg);
  const float sx = sel[b * 3 + 0], sy = sel[b * 3 + 1], sz = sel[b * 3 + 2];
  __syncthreads();
  for (int k0 = 0; k0 < KNN; k0 += 2) {
    if (tid < 2) {
      int idx = nbr[b * KNN + k0 + tid];
      relbuf[tid][0] = pts[3 * idx + 0] - sx;
      relbuf[tid][1] = pts[3 * idx + 1] - sy;
      relbuf[tid][2] = pts[3 * idx + 2] - sz;
    }
    __syncthreads();
    if (tid < 90) {
      int r = tid / 45, j = tid % 45, p = j / 3, c = j % 3;
      float rx = relbuf[r][0] - kpp[p * 3 + 0];
      float ry = relbuf[r][1] - kpp[p * 3 + 1];
      float rz = relbuf[r][2] - kpp[p * 3 + 2];
      float w = expf(inv2s2 * (rx * rx + ry * ry + rz * rz));
      abuf[r][j] = relbuf[r][c] * w;
    }
    __syncthreads();
    {
      int r = tid >> 7, o = tid & 127;
      float acc = 0.f;
#pragma unroll
      for (int j = 0; j < 45; ++j) acc += abuf[r][j] * kpw[j * 128 + o];
      h[(b * KNN + k0 + r) * 128 + o] = __float2half(fmaxf(acc, 0.f));
    }
    __syncthreads();
  }
}

// ---------------------------------------------------------------- w -> f16
__global__ __launch_bounds__(256) void convertw_kernel(
    const float* __restrict__ w, __half* __restrict__ wh) {
  int i = blockIdx.x * 256 + threadIdx.x;
  if (i < C2 * C1) wh[i] = __float2half(w[i]);
}

// ------------------------------------------------------- conv1 (f16 MFMA)
// Per block: point-batch row b x 128 output cols, K=128 fully staged in LDS.
// 4 waves x (2 n-tiles x 7 m-tiles) of mfma_f32_16x16x32_f16.
// Fused epilogue: bias+relu, per-(b,col) max/min (rows>=100 masked),
// per-col sum/sumsq atomics for BN stats.
__global__ __launch_bounds__(256) void conv1_mfma_kernel(
    const __half* __restrict__ h16, const __half* __restrict__ wh,
    const float* __restrict__ bias, float* __restrict__ featmax,
    float* __restrict__ featmin, float* __restrict__ bnsum,
    float* __restrict__ bnsq) {
  const int b = blockIdx.y;
  const int n0 = blockIdx.x * 128;
  const int tid = threadIdx.x;
  const int wave = tid >> 6, lane = tid & 63;
  const int lr = lane & 15, quad = lane >> 4;
  __shared__ __half Hs[112 * 136];  // +8 halves pad: uniform bank spread
  __shared__ __half Ws[128 * 136];

  for (int i = tid; i < 112 * 16; i += 256) {
    int row = i >> 4, seg = i & 15;
    float4 v = make_float4(0.f, 0.f, 0.f, 0.f);
    if (row < 100) v = *(const float4*)&h16[(b * 100 + row) * 128 + seg * 8];
    *(float4*)&Hs[row * 136 + seg * 8] = v;
  }
  for (int i = tid; i < 128 * 16; i += 256) {
    int row = i >> 4, seg = i & 15;
    *(float4*)&Ws[row * 136 + seg * 8] =
        *(const float4*)&wh[(n0 + row) * 128 + seg * 8];
  }
  __syncthreads();

  f32x4 acc[2][7];
#pragma unroll
  for (int t = 0; t < 2; ++t)
#pragma unroll
    for (int m = 0; m < 7; ++m) acc[t][m] = (f32x4)(0.f);

#pragma unroll
  for (int s = 0; s < 4; ++s) {
    half8 bfrag[2];
#pragma unroll
    for (int t = 0; t < 2; ++t)
      bfrag[t] =
          *(const half8*)&Ws[((wave * 2 + t) * 16 + lr) * 136 + s * 32 + quad * 8];
#pragma unroll
    for (int m = 0; m < 7; ++m) {
      half8 afrag = *(const half8*)&Hs[(m * 16 + lr) * 136 + s * 32 + quad * 8];
      acc[0][m] =
          __builtin_amdgcn_mfma_f32_16x16x32_f16(afrag, bfrag[0], acc[0][m], 0, 0, 0);
      acc[1][m] =
          __builtin_amdgcn_mfma_f32_16x16x32_f16(afrag, bfrag[1], acc[1][m], 0, 0, 0);
    }
  }

#pragma unroll
  for (int t = 0; t < 2; ++t) {
    int col = n0 + (wave * 2 + t) * 16 + lr;
    float bv = bias[col];
    float pmax = -1e30f, pmin = 1e30f, psum = 0.f, psq = 0.f;
#pragma unroll
    for (int m = 0; m < 7; ++m)
#pragma unroll
      for (int r = 0; r < 4; ++r) {
        int row = m * 16 + quad * 4 + r;
        if (row < 100) {
          float y = fmaxf(acc[t][m][r] + bv, 0.f);
          pmax = fmaxf(pmax, y);
          pmin = fminf(pmin, y);
          psum += y;
          psq += y * y;
        }
      }
    pmax = fmaxf(pmax, __shfl_xor(pmax, 16));
    pmax = fmaxf(pmax, __shfl_xor(pmax, 32));
    pmin = fminf(pmin, __shfl_xor(pmin, 16));
    pmin = fminf(pmin, __shfl_xor(pmin, 32));
    psum += __shfl_xor(psum, 16);
    psum += __shfl_xor(psum, 32);
    psq += __shfl_xor(psq, 16);
    psq += __shfl_xor(psq, 32);
    if (quad == 0) {
      featmax[b * C2 + col] = pmax;
      featmin[b * C2 + col] = pmin;
      atomicAdd(&bnsum[col], psum);
      atomicAdd(&bnsq[col], psq);
    }
  }
}

// ------------------------------------------------------- BN1 + max finalize
__global__ __launch_bounds__(256) void bn1max_kernel(
    const float* __restrict__ featmax, const float* __restrict__ featmin,
    const float* __restrict__ bnsum, const float* __restrict__ bnsq,
    const float* __restrict__ g, const float* __restrict__ bb,
    float* __restrict__ feat1) {
  int idx = blockIdx.x * 256 + threadIdx.x;
  if (idx >= NB * C2) return;
  int o = idx & (C2 - 1);
  const float invn = 1.f / (float)(NB * KNN);
  float m = bnsum[o] * invn;
  float v = bnsq[o] * invn - m * m;
  float a = g[o] / sqrtf(v + 1e-5f);
  float x = (a >= 0.f) ? featmax[idx] : featmin[idx];  // max of monotone map
  feat1[idx] = (x - m) * a + bb[o];
}

// ---------------------------------------------------------------- fc + stats
template <int KDIM>
__global__ __launch_bounds__(256) void fc_relu_stats_kernel(
    const float* __restrict__ x,  // [500][KDIM]
    const float* __restrict__ w,  // [N][KDIM]
    const float* __restrict__ bias, float* __restrict__ yraw,
    float* __restrict__ s, float* __restrict__ sq, int ncols) {
  const int r0 = blockIdx.x * 4;
  const int n0 = blockIdx.y * 64;
  const int tid = threadIdx.x;
  const int col = tid >> 2;  // 0..63
  const int row = tid & 3;
  __shared__ float xs[4][1028];
  __shared__ float ws[64][132];
  for (int f = tid; f < KDIM; f += 256) {  // KDIM float4's total
    int rr = f / (KDIM / 4), kq = (f % (KDIM / 4)) * 4;
    *(float4*)&xs[rr][kq] = *(const float4*)&x[(r0 + rr) * KDIM + kq];
  }
  float acc = 0.f;
  for (int kc = 0; kc < KDIM; kc += 128) {
    __syncthreads();
#pragma unroll
    for (int i = 0; i < 8; ++i) {
      int f = tid + i * 256;  // 0..2047
      int cr = f >> 5, kq = (f & 31) * 4;
      *(float4*)&ws[cr][kq] = *(const float4*)&w[(n0 + cr) * KDIM + kc + kq];
    }
    __syncthreads();
    for (int kk = 0; kk < 128; kk += 4) {
      float4 xv = *(float4*)&xs[row][kc + kk];
      float4 wv = *(float4*)&ws[col][kk];
      acc += xv.x * wv.x + xv.y * wv.y + xv.z * wv.z + xv.w * wv.w;
    }
  }
  float y = fmaxf(acc + bias[n0 + col], 0.f);
  yraw[(r0 + row) * ncols + n0 + col] = y;
  float ys = y, y2 = y * y;
  ys += __shfl_xor(ys, 1); y2 += __shfl_xor(y2, 1);
  ys += __shfl_xor(ys, 2); y2 += __shfl_xor(y2, 2);
  if (row == 0) {
    atomicAdd(&s[n0 + col], ys);
    atomicAdd(&sq[n0 + col], y2);
  }
}

// ---------------------------------------------------------------- BN finalize
__global__ __launch_bounds__(256) void bn_finalize_kernel(
    const float* __restrict__ yraw, const float* __restrict__ s,
    const float* __restrict__ sq, const float* __restrict__ g,
    const float* __restrict__ bb, float* __restrict__ out, int ncols) {
  int idx = blockIdx.x * 256 + threadIdx.x;
  if (idx >= NB * ncols) return;
  int o = idx & (ncols - 1);  // ncols is a power of two
  float m = s[o] * (1.f / (float)NB);
  float v = sq[o] * (1.f / (float)NB) - m * m;
  float a = g[o] / sqrtf(v + 1e-5f);
  out[idx] = (yraw[idx] - m) * a + bb[o];
}

// ---------------------------------------------------------------- fc3
__global__ __launch_bounds__(256) void fc3_kernel(
    const float* __restrict__ feat, const float* __restrict__ w,
    const float* __restrict__ bias, float* __restrict__ out) {
  int idx = blockIdx.x * 256 + threadIdx.x;
  if (idx >= NB * 3) return;
  int b = idx / 3, o = idx % 3;
  float acc = 0.f;
  for (int k = 0; k < C4; ++k) acc += feat[b * C4 + k] * w[o * C4 + k];
  out[idx] = acc + bias[o];
}

// ---------------------------------------------------------------- launch
extern "C" void kernel_launch(void* const* d_in, const int* in_sizes, int n_in,
                              void* d_out, int out_size, void* d_ws,
                              size_t ws_size, hipStream_t stream) {
  const float* pts = (const float*)d_in[0];
  const float* normal = (const float*)d_in[1];
  const float* kp_points = (const float*)d_in[2];
  const float* kp_weights = (const float*)d_in[3];
  const float* kp_sigma = (const float*)d_in[4];
  const float* conv1_w = (const float*)d_in[5];
  const float* conv1_b = (const float*)d_in[6];
  const float* bn1_g = (const float*)d_in[7];
  const float* bn1_b = (const float*)d_in[8];
  const float* fc1_w = (const float*)d_in[9];
  const float* fc1_b = (const float*)d_in[10];
  const float* bn4_g = (const float*)d_in[11];
  const float* bn4_b = (const float*)d_in[12];
  const float* fc2_w = (const float*)d_in[13];
  const float* fc2_b = (const float*)d_in[14];
  const float* bn5_g = (const float*)d_in[15];
  const float* bn5_b = (const float*)d_in[16];
  const float* fc3_w = (const float*)d_in[17];
  const float* fc3_b = (const float*)d_in[18];
  const int* index = (const int*)d_in[19];
  float* out = (float*)d_out;

  char* p = (char*)d_ws;
  auto carve = [&](size_t bytes) {
    void* r = (void*)p;
    p += (bytes + 255) & ~(size_t)255;
    return r;
  };
  float* sel = (float*)carve(NB * 3 * 4);
  int* nbr = (int*)carve(NB * KNN * 4);
  __half* h = (__half*)carve((size_t)NB * KNN * C1 * 2);
  __half* wh = (__half*)carve((size_t)C2 * C1 * 2);
  float* featmax = (float*)carve(NB * C2 * 4);
  float* featmin = (float*)carve(NB * C2 * 4);
  float* feat1 = (float*)carve(NB * C2 * 4);
  float* f2raw = (float*)carve(NB * C3 * 4);
  float* feat2 = (float*)carve(NB * C3 * 4);
  float* f3raw = (float*)carve(NB * C4 * 4);
  float* feat3 = (float*)carve(NB * C4 * 4);
  float* stats = (float*)carve((2 * C2 + 2 * C3 + 2 * C4) * 4);
  float* bnsum = stats;
  float* bnsq = stats + C2;
  float* s4 = stats + 2 * C2;
  float* sq4 = s4 + C3;
  float* s5 = sq4 + C3;
  float* sq5 = s5 + C4;

  hipMemsetAsync(stats, 0, (2 * C2 + 2 * C3 + 2 * C4) * 4, stream);

  gather_kernel<<<2, 256, 0, stream>>>(pts, normal, index, sel, out + NB * 3);
  knn_kernel<<<NB, 256, 0, stream>>>(pts, sel, nbr);
  convertw_kernel<<<(C2 * C1 + 255) / 256, 256, 0, stream>>>(conv1_w, wh);
  kpconv_kernel<<<NB, 256, 0, stream>>>(pts, sel, nbr, kp_points, kp_weights,
                                        kp_sigma, h);
  conv1_mfma_kernel<<<dim3(8, NB), 256, 0, stream>>>(h, wh, conv1_b, featmax,
                                                     featmin, bnsum, bnsq);
  bn1max_kernel<<<(NB * C2 + 255) / 256, 256, 0, stream>>>(
      featmax, featmin, bnsum, bnsq, bn1_g, bn1_b, feat1);
  fc_relu_stats_kernel<C2><<<dim3(125, C3 / 64), 256, 0, stream>>>(
      feat1, fc1_w, fc1_b, f2raw, s4, sq4, C3);
  bn_finalize_kernel<<<(NB * C3 + 255) / 256, 256, 0, stream>>>(
      f2raw, s4, sq4, bn4_g, bn4_b, feat2, C3);
  fc_relu_stats_kernel<C3><<<dim3(125, C4 / 64), 256, 0, stream>>>(
      feat2, fc2_w, fc2_b, f3raw, s5, sq5, C4);
  bn_finalize_kernel<<<(NB * C4 + 255) / 256, 256, 0, stream>>>(
      f3raw, s5, sq5, bn5_g, bn5_b, feat3, C4);
  fc3_kernel<<<(NB * 3 + 255) / 256, 256, 0, stream>>>(feat3, fc3_w, fc3_b,
                                                       out);
}

// Round 5
// 285.837 us; speedup vs baseline: 2.6537x; 1.1922x over previous
//
#include <hip/hip_runtime.h>
#include <hip/hip_fp16.h>

#define NPTS 100000
#define NB 500
#define KNN 100
#define KPN 15
#define C1 128
#define C2 1024
#define C3 512
#define C4 256

typedef _Float16 half8 __attribute__((ext_vector_type(8)));
typedef float f32x4 __attribute__((ext_vector_type(4)));

// ---------------------------------------------------------------- gather
__global__ __launch_bounds__(256) void gather_kernel(
    const float* __restrict__ pts, const float* __restrict__ normal,
    const int* __restrict__ index, float* __restrict__ sel,
    float* __restrict__ out2) {
  int b = blockIdx.x * 256 + threadIdx.x;
  if (b >= NB) return;
  int i = index[b];
  sel[b * 3 + 0] = pts[3 * i + 0];
  sel[b * 3 + 1] = pts[3 * i + 1];
  sel[b * 3 + 2] = pts[3 * i + 2];
  out2[b * 3 + 0] = normal[3 * i + 0];
  out2[b * 3 + 1] = normal[3 * i + 1];
  out2[b * 3 + 2] = normal[3 * i + 2];
}

// ---------------------------------------------------------------- kNN v3
// 1024 threads/block (16 waves) for latency hiding; one 12-bit histogram
// scan + collect scan, exact rank-select on the boundary bin.
#define KT 1024

__device__ __forceinline__ unsigned linf_bits(float px, float py, float pz,
                                              float sx, float sy, float sz) {
  float dx = fabsf(px - sx), dy = fabsf(py - sy), dz = fabsf(pz - sz);
  return __float_as_uint(fmaxf(fmaxf(dx, dy), dz));
}

__global__ __launch_bounds__(KT) void knn_kernel(
    const float* __restrict__ pts, const float* __restrict__ sel,
    int* __restrict__ nbr) {
  const int b = blockIdx.x;
  const int tid = threadIdx.x;
  __shared__ unsigned hist[4096];
  __shared__ unsigned chunksum[256];
  __shared__ unsigned s_prefix;
  __shared__ int s_kneed, s_base, s_cnt, s_direct, s_cnt2;
  __shared__ unsigned cand_bits[1024];
  __shared__ int cand_idx[1024];

  const float sx = sel[b * 3 + 0], sy = sel[b * 3 + 1], sz = sel[b * 3 + 2];
  const float4* base4 = (const float4*)pts;

  for (int j = tid; j < 4096; j += KT) hist[j] = 0;
  __syncthreads();
  {
    float4 c[6], n[6];
    int i0 = tid * 8;
#pragma unroll
    for (int j = 0; j < 6; ++j) c[j] = base4[(i0 * 3) / 4 + j];
    for (int it = 0; it < 12; ++it) {
      if (it + 1 < 12) {
        int i1 = (it + 1) * 8192 + tid * 8;
#pragma unroll
        for (int j = 0; j < 6; ++j) n[j] = base4[(i1 * 3) / 4 + j];
      }
      float px[8], py[8], pz[8];
      px[0] = c[0].x; py[0] = c[0].y; pz[0] = c[0].z;
      px[1] = c[0].w; py[1] = c[1].x; pz[1] = c[1].y;
      px[2] = c[1].z; py[2] = c[1].w; pz[2] = c[2].x;
      px[3] = c[2].y; py[3] = c[2].z; pz[3] = c[2].w;
      px[4] = c[3].x; py[4] = c[3].y; pz[4] = c[3].z;
      px[5] = c[3].w; py[5] = c[4].x; pz[5] = c[4].y;
      px[6] = c[4].z; py[6] = c[4].w; pz[6] = c[5].x;
      px[7] = c[5].y; py[7] = c[5].z; pz[7] = c[5].w;
#pragma unroll
      for (int j = 0; j < 8; ++j) {
        unsigned bits = linf_bits(px[j], py[j], pz[j], sx, sy, sz);
        atomicAdd(&hist[bits >> 19], 1u);
      }
#pragma unroll
      for (int j = 0; j < 6; ++j) c[j] = n[j];
    }
    for (int i = 98304 + tid; i < NPTS; i += KT) {
      unsigned bits =
          linf_bits(pts[3 * i], pts[3 * i + 1], pts[3 * i + 2], sx, sy, sz);
      atomicAdd(&hist[bits >> 19], 1u);
    }
  }

  unsigned shift = 19, prefix = 0, pendwidth = 0;
  int kneed = KNN;
  for (int pass = 0;; ++pass) {
    __syncthreads();
    if (tid < 256) {
      unsigned csum = 0;
      for (int j = 0; j < 16; ++j) csum += hist[tid * 16 + j];
      chunksum[tid] = csum;
    }
    __syncthreads();
    if (tid == 0) {
      unsigned need = (unsigned)kneed;
      unsigned cum = 0;
      int chunk = 0;
      while (chunk < 255 && cum + chunksum[chunk] < need) {
        cum += chunksum[chunk];
        ++chunk;
      }
      int bin = chunk * 16;
      while (cum + hist[bin] < need) {
        cum += hist[bin];
        ++bin;
      }
      s_kneed = (int)(need - cum);
      s_base = (int)cum;
      s_prefix = (unsigned)bin;
      s_cnt = (int)hist[bin];
    }
    __syncthreads();
    int bincnt = s_cnt;
    kneed = s_kneed;
    prefix = (pass == 0) ? s_prefix : ((prefix << pendwidth) | s_prefix);
    if (bincnt <= 1024 || shift == 0) break;
    unsigned fshift = shift;
    unsigned nshift = (shift == 19) ? 7u : 0u;
    pendwidth = (shift == 19) ? 12u : 7u;
    __syncthreads();
    for (int j = tid; j < 4096; j += KT) hist[j] = 0;
    __syncthreads();
    for (int i = tid; i < NPTS; i += KT) {
      unsigned bits =
          linf_bits(pts[3 * i], pts[3 * i + 1], pts[3 * i + 2], sx, sy, sz);
      if ((bits >> fshift) == prefix) {
        unsigned bin = (nshift == 7u) ? ((bits >> 7) & 4095u) : (bits & 127u);
        atomicAdd(&hist[bin], 1u);
      }
    }
    shift = nshift;
  }

  if (tid == 0) {
    s_direct = 0;
    s_cnt2 = 0;
  }
  __syncthreads();
  {
    float4 c[6], n[6];
    int i0 = tid * 8;
#pragma unroll
    for (int j = 0; j < 6; ++j) c[j] = base4[(i0 * 3) / 4 + j];
    for (int it = 0; it < 12; ++it) {
      if (it + 1 < 12) {
        int i1 = (it + 1) * 8192 + tid * 8;
#pragma unroll
        for (int j = 0; j < 6; ++j) n[j] = base4[(i1 * 3) / 4 + j];
      }
      float px[8], py[8], pz[8];
      px[0] = c[0].x; py[0] = c[0].y; pz[0] = c[0].z;
      px[1] = c[0].w; py[1] = c[1].x; pz[1] = c[1].y;
      px[2] = c[1].z; py[2] = c[1].w; pz[2] = c[2].x;
      px[3] = c[2].y; py[3] = c[2].z; pz[3] = c[2].w;
      px[4] = c[3].x; py[4] = c[3].y; pz[4] = c[3].z;
      px[5] = c[3].w; py[5] = c[4].x; pz[5] = c[4].y;
      px[6] = c[4].z; py[6] = c[4].w; pz[6] = c[5].x;
      px[7] = c[5].y; py[7] = c[5].z; pz[7] = c[5].w;
      int ibase = it * 8192 + tid * 8;
#pragma unroll
      for (int j = 0; j < 8; ++j) {
        unsigned bits = linf_bits(px[j], py[j], pz[j], sx, sy, sz);
        unsigned v = bits >> shift;
        if (v < prefix) {
          int pos = atomicAdd(&s_direct, 1);
          nbr[b * KNN + pos] = ibase + j;
        } else if (v == prefix) {
          int e = atomicAdd(&s_cnt2, 1);
          if (e < 1024) {
            cand_bits[e] = bits;
            cand_idx[e] = ibase + j;
          }
        }
      }
#pragma unroll
      for (int j = 0; j < 6; ++j) c[j] = n[j];
    }
    for (int i = 98304 + tid; i < NPTS; i += KT) {
      unsigned bits =
          linf_bits(pts[3 * i], pts[3 * i + 1], pts[3 * i + 2], sx, sy, sz);
      unsigned v = bits >> shift;
      if (v < prefix) {
        int pos = atomicAdd(&s_direct, 1);
        nbr[b * KNN + pos] = i;
      } else if (v == prefix) {
        int e = atomicAdd(&s_cnt2, 1);
        if (e < 1024) {
          cand_bits[e] = bits;
          cand_idx[e] = i;
        }
      }
    }
  }
  __syncthreads();

  int m = s_cnt2 < 1024 ? s_cnt2 : 1024;
  int base = s_direct;
  for (int c = tid; c < m; c += KT) {
    unsigned bc = cand_bits[c];
    int ic = cand_idx[c];
    int rank = 0;
    for (int j = 0; j < m; ++j) {
      unsigned bj = cand_bits[j];
      rank += (bj < bc || (bj == bc && cand_idx[j] < ic)) ? 1 : 0;
    }
    if (rank < kneed) nbr[b * KNN + base + rank] = ic;
  }
}

// ------------------------------------------------- weight converts (f16)
// wh [1024][128] <- conv1_w ; kpwT hi/lo [128][64] <- kp_weights^T (K pad
// 45->64). hi/lo split: w = hi + lo with hi=f16(w), lo=f16(w-hi) so the
// MFMA input error is O(2^-22) instead of 2^-11.
__global__ __launch_bounds__(256) void convert_kernel(
    const float* __restrict__ w1, const float* __restrict__ kpw,
    __half* __restrict__ wh, __half* __restrict__ kpwT_hi,
    __half* __restrict__ kpwT_lo) {
  int i = blockIdx.x * 256 + threadIdx.x;
  if (i < C2 * C1) wh[i] = __float2half(w1[i]);
  if (i < 128 * 64) {
    int o = i >> 6, j = i & 63;
    float v = (j < 45) ? kpw[j * 128 + o] : 0.f;
    __half hi = __float2half_rn(v);
    kpwT_hi[i] = hi;
    kpwT_lo[i] = __float2half_rn(v - __half2float(hi));
  }
}

// ------------------------------------------------- KPConv (f16 MFMA, hi/lo)
// h[100x128] = relu(A[100x64] x kpwT^T); A[k][p*3+c] = rel[k][c]*gauss(k,p).
// A and B both hi/lo split; acc = Ahi*Bhi + Ahi*Blo + Alo*Bhi (fp32 acc).
__global__ __launch_bounds__(256) void kpconv_mfma_kernel(
    const float* __restrict__ pts, const float* __restrict__ sel,
    const int* __restrict__ nbr, const float* __restrict__ kp_points,
    const __half* __restrict__ kpwT_hi, const __half* __restrict__ kpwT_lo,
    const float* __restrict__ kp_sigma, __half* __restrict__ h) {
  const int b = blockIdx.x;
  const int tid = threadIdx.x;
  const int wave = tid >> 6, lane = tid & 63;
  const int lr = lane & 15, quad = lane >> 4;
  __shared__ __half As_hi[112 * 72];  // +8 pad
  __shared__ __half As_lo[112 * 72];
  __shared__ __half Bs_hi[128 * 72];
  __shared__ __half Bs_lo[128 * 72];
  __shared__ float rel[100][4];
  __shared__ float kpp[48];

  for (int i = tid; i < 128 * 8; i += 256) {
    int row = i >> 3, seg = i & 7;
    *(float4*)&Bs_hi[row * 72 + seg * 8] =
        *(const float4*)&kpwT_hi[row * 64 + seg * 8];
    *(float4*)&Bs_lo[row * 72 + seg * 8] =
        *(const float4*)&kpwT_lo[row * 64 + seg * 8];
  }
  {
    float4 z = make_float4(0.f, 0.f, 0.f, 0.f);
    for (int i = tid; i < 112 * 8; i += 256) {
      int row = i >> 3, seg = i & 7;
      *(float4*)&As_hi[row * 72 + seg * 8] = z;
      *(float4*)&As_lo[row * 72 + seg * 8] = z;
    }
  }
  if (tid < 45) kpp[tid] = kp_points[tid];
  if (tid < 100) {
    int idx = nbr[b * KNN + tid];
    rel[tid][0] = pts[3 * idx + 0] - sel[b * 3 + 0];
    rel[tid][1] = pts[3 * idx + 1] - sel[b * 3 + 1];
    rel[tid][2] = pts[3 * idx + 2] - sel[b * 3 + 2];
  }
  __syncthreads();

  const float sg = kp_sigma[0];
  const float inv2s2 = -0.5f / (sg * sg);
  for (int i = tid; i < 100 * KPN; i += 256) {
    int k = i / KPN, p = i - k * KPN;
    float rx = rel[k][0] - kpp[p * 3 + 0];
    float ry = rel[k][1] - kpp[p * 3 + 1];
    float rz = rel[k][2] - kpp[p * 3 + 2];
    float w = expf(inv2s2 * (rx * rx + ry * ry + rz * rz));
#pragma unroll
    for (int c = 0; c < 3; ++c) {
      float a = rel[k][c] * w;
      __half hi = __float2half_rn(a);
      As_hi[k * 72 + p * 3 + c] = hi;
      As_lo[k * 72 + p * 3 + c] = __float2half_rn(a - __half2float(hi));
    }
  }
  __syncthreads();

  f32x4 acc[2][7];
#pragma unroll
  for (int t = 0; t < 2; ++t)
#pragma unroll
    for (int m = 0; m < 7; ++m) acc[t][m] = (f32x4)(0.f);

#pragma unroll
  for (int s = 0; s < 2; ++s) {
    half8 bhi[2], blo[2];
#pragma unroll
    for (int t = 0; t < 2; ++t) {
      int boff = ((wave * 2 + t) * 16 + lr) * 72 + s * 32 + quad * 8;
      bhi[t] = *(const half8*)&Bs_hi[boff];
      blo[t] = *(const half8*)&Bs_lo[boff];
    }
#pragma unroll
    for (int m = 0; m < 7; ++m) {
      int aoff = (m * 16 + lr) * 72 + s * 32 + quad * 8;
      half8 ahi = *(const half8*)&As_hi[aoff];
      half8 alo = *(const half8*)&As_lo[aoff];
#pragma unroll
      for (int t = 0; t < 2; ++t) {
        acc[t][m] = __builtin_amdgcn_mfma_f32_16x16x32_f16(ahi, bhi[t],
                                                           acc[t][m], 0, 0, 0);
        acc[t][m] = __builtin_amdgcn_mfma_f32_16x16x32_f16(ahi, blo[t],
                                                           acc[t][m], 0, 0, 0);
        acc[t][m] = __builtin_amdgcn_mfma_f32_16x16x32_f16(alo, bhi[t],
                                                           acc[t][m], 0, 0, 0);
      }
    }
  }

#pragma unroll
  for (int t = 0; t < 2; ++t) {
    int col = (wave * 2 + t) * 16 + lr;
#pragma unroll
    for (int m = 0; m < 7; ++m)
#pragma unroll
      for (int r = 0; r < 4; ++r) {
        int row = m * 16 + quad * 4 + r;
        if (row < 100)
          h[(b * KNN + row) * 128 + col] =
              __float2half_rn(fmaxf(acc[t][m][r], 0.f));
      }
  }
}

// ------------------------------------------------------- conv1 (f16 MFMA)
__global__ __launch_bounds__(256) void conv1_mfma_kernel(
    const __half* __restrict__ h16, const __half* __restrict__ wh,
    const float* __restrict__ bias, float* __restrict__ featmax,
    float* __restrict__ featmin, float* __restrict__ bnsum,
    float* __restrict__ bnsq) {
  const int b = blockIdx.y;
  const int n0 = blockIdx.x * 128;
  const int tid = threadIdx.x;
  const int wave = tid >> 6, lane = tid & 63;
  const int lr = lane & 15, quad = lane >> 4;
  __shared__ __half Hs[112 * 136];
  __shared__ __half Ws[128 * 136];

  for (int i = tid; i < 112 * 16; i += 256) {
    int row = i >> 4, seg = i & 15;
    float4 v = make_float4(0.f, 0.f, 0.f, 0.f);
    if (row < 100) v = *(const float4*)&h16[(b * 100 + row) * 128 + seg * 8];
    *(float4*)&Hs[row * 136 + seg * 8] = v;
  }
  for (int i = tid; i < 128 * 16; i += 256) {
    int row = i >> 4, seg = i & 15;
    *(float4*)&Ws[row * 136 + seg * 8] =
        *(const float4*)&wh[(n0 + row) * 128 + seg * 8];
  }
  __syncthreads();

  f32x4 acc[2][7];
#pragma unroll
  for (int t = 0; t < 2; ++t)
#pragma unroll
    for (int m = 0; m < 7; ++m) acc[t][m] = (f32x4)(0.f);

#pragma unroll
  for (int s = 0; s < 4; ++s) {
    half8 bfrag[2];
#pragma unroll
    for (int t = 0; t < 2; ++t)
      bfrag[t] =
          *(const half8*)&Ws[((wave * 2 + t) * 16 + lr) * 136 + s * 32 + quad * 8];
#pragma unroll
    for (int m = 0; m < 7; ++m) {
      half8 afrag = *(const half8*)&Hs[(m * 16 + lr) * 136 + s * 32 + quad * 8];
      acc[0][m] =
          __builtin_amdgcn_mfma_f32_16x16x32_f16(afrag, bfrag[0], acc[0][m], 0, 0, 0);
      acc[1][m] =
          __builtin_amdgcn_mfma_f32_16x16x32_f16(afrag, bfrag[1], acc[1][m], 0, 0, 0);
    }
  }

#pragma unroll
  for (int t = 0; t < 2; ++t) {
    int col = n0 + (wave * 2 + t) * 16 + lr;
    float bv = bias[col];
    float pmax = -1e30f, pmin = 1e30f, psum = 0.f, psq = 0.f;
#pragma unroll
    for (int m = 0; m < 7; ++m)
#pragma unroll
      for (int r = 0; r < 4; ++r) {
        int row = m * 16 + quad * 4 + r;
        if (row < 100) {
          float y = fmaxf(acc[t][m][r] + bv, 0.f);
          pmax = fmaxf(pmax, y);
          pmin = fminf(pmin, y);
          psum += y;
          psq += y * y;
        }
      }
    pmax = fmaxf(pmax, __shfl_xor(pmax, 16));
    pmax = fmaxf(pmax, __shfl_xor(pmax, 32));
    pmin = fminf(pmin, __shfl_xor(pmin, 16));
    pmin = fminf(pmin, __shfl_xor(pmin, 32));
    psum += __shfl_xor(psum, 16);
    psum += __shfl_xor(psum, 32);
    psq += __shfl_xor(psq, 16);
    psq += __shfl_xor(psq, 32);
    if (quad == 0) {
      featmax[b * C2 + col] = pmax;
      featmin[b * C2 + col] = pmin;
      atomicAdd(&bnsum[col], psum);
      atomicAdd(&bnsq[col], psq);
    }
  }
}

// ------------------------------------------------------- BN1 + max finalize
__global__ __launch_bounds__(256) void bn1max_kernel(
    const float* __restrict__ featmax, const float* __restrict__ featmin,
    const float* __restrict__ bnsum, const float* __restrict__ bnsq,
    const float* __restrict__ g, const float* __restrict__ bb,
    float* __restrict__ feat1) {
  int idx = blockIdx.x * 256 + threadIdx.x;
  if (idx >= NB * C2) return;
  int o = idx & (C2 - 1);
  const float invn = 1.f / (float)(NB * KNN);
  float m = bnsum[o] * invn;
  float v = bnsq[o] * invn - m * m;
  float a = g[o] / sqrtf(v + 1e-5f);
  float x = (a >= 0.f) ? featmax[idx] : featmin[idx];  // max of monotone map
  feat1[idx] = (x - m) * a + bb[o];
}

// ---------------------------------------------------------------- fc + stats
template <int KDIM>
__global__ __launch_bounds__(256) void fc_relu_stats_kernel(
    const float* __restrict__ x,  // [500][KDIM]
    const float* __restrict__ w,  // [N][KDIM]
    const float* __restrict__ bias, float* __restrict__ yraw,
    float* __restrict__ s, float* __restrict__ sq, int ncols) {
  const int r0 = blockIdx.x * 4;
  const int n0 = blockIdx.y * 64;
  const int tid = threadIdx.x;
  const int col = tid >> 2;  // 0..63
  const int row = tid & 3;
  __shared__ float xs[4][1028];
  __shared__ float ws[64][132];
  for (int f = tid; f < KDIM; f += 256) {  // KDIM float4's total
    int rr = f / (KDIM / 4), kq = (f % (KDIM / 4)) * 4;
    *(float4*)&xs[rr][kq] = *(const float4*)&x[(r0 + rr) * KDIM + kq];
  }
  float acc = 0.f;
  for (int kc = 0; kc < KDIM; kc += 128) {
    __syncthreads();
#pragma unroll
    for (int i = 0; i < 8; ++i) {
      int f = tid + i * 256;  // 0..2047
      int cr = f >> 5, kq = (f & 31) * 4;
      *(float4*)&ws[cr][kq] = *(const float4*)&w[(n0 + cr) * KDIM + kc + kq];
    }
    __syncthreads();
    for (int kk = 0; kk < 128; kk += 4) {
      float4 xv = *(float4*)&xs[row][kc + kk];
      float4 wv = *(float4*)&ws[col][kk];
      acc += xv.x * wv.x + xv.y * wv.y + xv.z * wv.z + xv.w * wv.w;
    }
  }
  float y = fmaxf(acc + bias[n0 + col], 0.f);
  yraw[(r0 + row) * ncols + n0 + col] = y;
  float ys = y, y2 = y * y;
  ys += __shfl_xor(ys, 1); y2 += __shfl_xor(y2, 1);
  ys += __shfl_xor(ys, 2); y2 += __shfl_xor(y2, 2);
  if (row == 0) {
    atomicAdd(&s[n0 + col], ys);
    atomicAdd(&sq[n0 + col], y2);
  }
}

// ---------------------------------------------------------------- BN finalize
__global__ __launch_bounds__(256) void bn_finalize_kernel(
    const float* __restrict__ yraw, const float* __restrict__ s,
    const float* __restrict__ sq, const float* __restrict__ g,
    const float* __restrict__ bb, float* __restrict__ out, int ncols) {
  int idx = blockIdx.x * 256 + threadIdx.x;
  if (idx >= NB * ncols) return;
  int o = idx & (ncols - 1);  // ncols is a power of two
  float m = s[o] * (1.f / (float)NB);
  float v = sq[o] * (1.f / (float)NB) - m * m;
  float a = g[o] / sqrtf(v + 1e-5f);
  out[idx] = (yraw[idx] - m) * a + bb[o];
}

// ---------------------------------------------------------------- fc3
__global__ __launch_bounds__(256) void fc3_kernel(
    const float* __restrict__ feat, const float* __restrict__ w,
    const float* __restrict__ bias, float* __restrict__ out) {
  int idx = blockIdx.x * 256 + threadIdx.x;
  if (idx >= NB * 3) return;
  int b = idx / 3, o = idx % 3;
  float acc = 0.f;
  for (int k = 0; k < C4; ++k) acc += feat[b * C4 + k] * w[o * C4 + k];
  out[idx] = acc + bias[o];
}

// ---------------------------------------------------------------- launch
extern "C" void kernel_launch(void* const* d_in, const int* in_sizes, int n_in,
                              void* d_out, int out_size, void* d_ws,
                              size_t ws_size, hipStream_t stream) {
  const float* pts = (const float*)d_in[0];
  const float* normal = (const float*)d_in[1];
  const float* kp_points = (const float*)d_in[2];
  const float* kp_weights = (const float*)d_in[3];
  const float* kp_sigma = (const float*)d_in[4];
  const float* conv1_w = (const float*)d_in[5];
  const float* conv1_b = (const float*)d_in[6];
  const float* bn1_g = (const float*)d_in[7];
  const float* bn1_b = (const float*)d_in[8];
  const float* fc1_w = (const float*)d_in[9];
  const float* fc1_b = (const float*)d_in[10];
  const float* bn4_g = (const float*)d_in[11];
  const float* bn4_b = (const float*)d_in[12];
  const float* fc2_w = (const float*)d_in[13];
  const float* fc2_b = (const float*)d_in[14];
  const float* bn5_g = (const float*)d_in[15];
  const float* bn5_b = (const float*)d_in[16];
  const float* fc3_w = (const float*)d_in[17];
  const float* fc3_b = (const float*)d_in[18];
  const int* index = (const int*)d_in[19];
  float* out = (float*)d_out;

  char* p = (char*)d_ws;
  auto carve = [&](size_t bytes) {
    void* r = (void*)p;
    p += (bytes + 255) & ~(size_t)255;
    return r;
  };
  float* sel = (float*)carve(NB * 3 * 4);
  int* nbr = (int*)carve(NB * KNN * 4);
  __half* h = (__half*)carve((size_t)NB * KNN * C1 * 2);
  __half* wh = (__half*)carve((size_t)C2 * C1 * 2);
  __half* kpwT_hi = (__half*)carve((size_t)128 * 64 * 2);
  __half* kpwT_lo = (__half*)carve((size_t)128 * 64 * 2);
  float* featmax = (float*)carve(NB * C2 * 4);
  float* featmin = (float*)carve(NB * C2 * 4);
  float* feat1 = (float*)carve(NB * C2 * 4);
  float* f2raw = (float*)carve(NB * C3 * 4);
  float* feat2 = (float*)carve(NB * C3 * 4);
  float* f3raw = (float*)carve(NB * C4 * 4);
  float* feat3 = (float*)carve(NB * C4 * 4);
  float* stats = (float*)carve((2 * C2 + 2 * C3 + 2 * C4) * 4);
  float* bnsum = stats;
  float* bnsq = stats + C2;
  float* s4 = stats + 2 * C2;
  float* sq4 = s4 + C3;
  float* s5 = sq4 + C3;
  float* sq5 = s5 + C4;

  hipMemsetAsync(stats, 0, (2 * C2 + 2 * C3 + 2 * C4) * 4, stream);

  gather_kernel<<<2, 256, 0, stream>>>(pts, normal, index, sel, out + NB * 3);
  knn_kernel<<<NB, KT, 0, stream>>>(pts, sel, nbr);
  convert_kernel<<<(C2 * C1 + 255) / 256, 256, 0, stream>>>(
      conv1_w, kp_weights, wh, kpwT_hi, kpwT_lo);
  kpconv_mfma_kernel<<<NB, 256, 0, stream>>>(pts, sel, nbr, kp_points, kpwT_hi,
                                             kpwT_lo, kp_sigma, h);
  conv1_mfma_kernel<<<dim3(8, NB), 256, 0, stream>>>(h, wh, conv1_b, featmax,
                                                     featmin, bnsum, bnsq);
  bn1max_kernel<<<(NB * C2 + 255) / 256, 256, 0, stream>>>(
      featmax, featmin, bnsum, bnsq, bn1_g, bn1_b, feat1);
  fc_relu_stats_kernel<C2><<<dim3(125, C3 / 64), 256, 0, stream>>>(
      feat1, fc1_w, fc1_b, f2raw, s4, sq4, C3);
  bn_finalize_kernel<<<(NB * C3 + 255) / 256, 256, 0, stream>>>(
      f2raw, s4, sq4, bn4_g, bn4_b, feat2, C3);
  fc_relu_stats_kernel<C3><<<dim3(125, C4 / 64), 256, 0, stream>>>(
      feat2, fc2_w, fc2_b, f3raw, s5, sq5, C4);
  bn_finalize_kernel<<<(NB * C4 + 255) / 256, 256, 0, stream>>>(
      f3raw, s5, sq5, bn5_g, bn5_b, feat3, C4);
  fc3_kernel<<<(NB * 3 + 255) / 256, 256, 0, stream>>>(feat3, fc3_w, fc3_b,
                                                       out);
}